// Round 18
// baseline (303.562 us; speedup 1.0000x reference)
//
#include <hip/hip_runtime.h>
#include <cmath>

#define NN 4096
#define BB 4
#define CCH 8

// ---- workspace float offsets
#define OFF_W3JVAL 0         // 2670 (pad 2688)
#define OFF_W3JOUT 2688      // 10648 -> 13336 (pad 13440)
#define OFF_CTX0   13568     // 4 partials x 4*4096*96 floats -> ends 6305024 fl
#define CTXS       1572864
// ---- byte offsets, 16B aligned (after ctx: 6305024*4 = 25220096)
#define OFFB_KGH   25220096ULL   // u16[4*4096*32] = 1048576 B
#define OFFB_KGL   26268672ULL
#define OFFB_VG    27317248ULL   // u16[4*64*96*64] fp16 = 3145728 B
#define OFFB_WBH   30462976ULL   // u16[96*160] = 30720 B
#define OFFB_WBL   30493696ULL   // end 30524416

typedef short s16x8 __attribute__((ext_vector_type(8)));
typedef _Float16 f16x8 __attribute__((ext_vector_type(8)));
typedef float f32x4 __attribute__((ext_vector_type(4)));
typedef unsigned int u32x4 __attribute__((ext_vector_type(4)));
typedef unsigned int u32x2 __attribute__((ext_vector_type(2)));

static __device__ __forceinline__ unsigned short f2bf(float x){
  unsigned u = __float_as_uint(x);
  return (unsigned short)((u + 0x7FFFu + ((u >> 16) & 1u)) >> 16);
}
static __device__ __forceinline__ float bf2f(unsigned short h){
  return __uint_as_float(((unsigned)h) << 16);
}
static __device__ __forceinline__ unsigned pk2r(float v){
  unsigned short h = f2bf(v);
  unsigned short l = f2bf(v - bf2f(h));
  return ((unsigned)l << 16) | (unsigned)h;
}
static __device__ __forceinline__ unsigned short f2h(float x){
  return __builtin_bit_cast(unsigned short, (_Float16)x);
}
static __device__ __forceinline__ void unpk(u32x4 a, u32x4 b, s16x8& h, s16x8& l){
  u32x4 hw = { __builtin_amdgcn_perm(a[1],a[0],0x05040100u),
               __builtin_amdgcn_perm(a[3],a[2],0x05040100u),
               __builtin_amdgcn_perm(b[1],b[0],0x05040100u),
               __builtin_amdgcn_perm(b[3],b[2],0x05040100u)};
  u32x4 lw = { __builtin_amdgcn_perm(a[1],a[0],0x07060302u),
               __builtin_amdgcn_perm(a[3],a[2],0x07060302u),
               __builtin_amdgcn_perm(b[1],b[0],0x07060302u),
               __builtin_amdgcn_perm(b[3],b[2],0x07060302u)};
  h = __builtin_bit_cast(s16x8, hw);
  l = __builtin_bit_cast(s16x8, lw);
}
// barrier ordering LDS only: global loads stay in flight (no vmcnt drain).
static __device__ __forceinline__ void barrier_lds(){
  __asm__ volatile("s_waitcnt lgkmcnt(0)\n\ts_barrier" ::: "memory");
}

// ---------------------------------------------------------------- k_tab
// Wigner-3j builder, grid 14 x 256; sparse-Q contraction (<=8 terms/element).
static __device__ __forceinline__ void qent(int l, int r, int c, double& re, double& im){
  re=0.0; im=0.0;
  double s = ((l&3)==2)? -1.0 : 1.0;
  const double rs2 = 0.70710678118654752440;
  if(r < l){
    if(c == 2*l - r) re = s*rs2;
    else if(c == r)  im = -s*rs2;
  } else if(r == l){
    if(c == l) re = s;
  } else {
    double sg = ((r-l)&1)? -1.0 : 1.0;
    if(c == r) re = s*sg*rs2;
    else if(c == 2*l - r) im = s*sg*rs2;
  }
}
__global__ __launch_bounds__(256) void k_tab(float* __restrict__ Wv, float* __restrict__ Wo){
  __shared__ double Cc[2197];
  __shared__ double red[256];
  __shared__ double factS[20];
  int t = threadIdx.x;
  int p = blockIdx.x;
  if(t==0){
    double f=1.0; factS[0]=1.0;
    for(int i=1;i<20;i++){ f*=(double)i; factS[i]=f; }
  }
  const int L1[14]={4,4,6,4,6,6, 4,4,6,6,4,4,6,6};
  const int L2[14]={0,2,2,2,0,2, 4,6,4,6,4,6,4,6};
  const int L3[14]={4,4,4,6,6,6, 4,4,4,4,6,6,6,6};
  const int OFF[14]={0,81,486,1071,1656,1825, 0,729,1782,2835,4356,5409,6930,8451};
  int l1=L1[p], l2=L2[p], l3=L3[p];
  int d1=2*l1+1, d2=2*l2+1, d3=2*l3+1;
  int tot = d1*d2*d3;
  float* dst = (p<6) ? (Wv+OFF[p]) : (Wo+OFF[p]);
  double scale = (p<6) ? sqrt((2.0*l3+1.0)/24.0) : sqrt((2.0*l3+1.0)/256.0);
  __syncthreads();
  for(int e=t; e<tot; e+=256){
    int i = e/(d2*d3), rem = e - i*(d2*d3), j = rem/d3, k = rem - j*d3;
    int m1=i-l1, m2=j-l2, m3=k-l3;
    double v=0.0;
    if(m1+m2==m3){
      double pref = sqrt((2.0*l3+1.0)*factS[l3+l1-l2]*factS[l3-l1+l2]*factS[l1+l2-l3]/factS[l1+l2+l3+1]);
      pref *= sqrt(factS[l3+m3]*factS[l3-m3]*factS[l1-m1]*factS[l1+m1]*factS[l2-m2]*factS[l2+m2]);
      double s=0.0;
      for(int kk=0; kk<=l1+l2-l3; kk++){
        int dd0=kk, dd1=l1+l2-l3-kk, dd2=l1-m1-kk, dd3=l2+m2-kk, dd4=l3-l2+m1+kk, dd5=l3-l1-m2+kk;
        int mn=dd0;
        if(dd1<mn)mn=dd1; if(dd2<mn)mn=dd2; if(dd3<mn)mn=dd3; if(dd4<mn)mn=dd4; if(dd5<mn)mn=dd5;
        if(mn<0) continue;
        double prod = factS[dd0]*factS[dd1]*factS[dd2]*factS[dd3]*factS[dd4]*factS[dd5];
        s += ((kk&1)? -1.0:1.0)/prod;
      }
      v = pref*s;
    }
    Cc[e]=v;
  }
  __syncthreads();
  double crloc[9];
  double nacc=0.0;
  #pragma unroll
  for(int itr=0; itr<9; ++itr){
    int e = t + itr*256;
    double re = 0.0;
    if(e < tot){
      int j = e/(d2*d3), rem = e - j*(d2*d3), l = rem/d3, n = rem - l*d3;
      #pragma unroll
      for(int ii=0; ii<2; ii++){
        int i = ii ? (2*l1 - j) : j;
        double q1r,q1i; qent(l1,i,j,q1r,q1i);
        if(ii && i==j){ q1r=0.0; q1i=0.0; }
        #pragma unroll
        for(int kk=0; kk<2; kk++){
          int k = kk ? (2*l2 - l) : l;
          double q2r,q2i; qent(l2,k,l,q2r,q2i);
          if(kk && k==l){ q2r=0.0; q2i=0.0; }
          double ar = q1r*q2r - q1i*q2i;
          double ai = q1r*q2i + q1i*q2r;
          #pragma unroll
          for(int mm=0; mm<2; mm++){
            int m = mm ? (2*l3 - n) : n;
            double q3r,q3i; qent(l3,m,n,q3r,q3i);
            if(mm && m==n){ q3r=0.0; q3i=0.0; }
            double coef = ar*q3r + ai*q3i;
            re += coef * Cc[(i*d2+k)*d3+m];
          }
        }
      }
    }
    crloc[itr]=re;
    nacc += re*re;
  }
  red[t]=nacc;
  __syncthreads();
  #pragma unroll
  for(int s=128;s>0;s>>=1){
    if(t<s) red[t]+=red[t+s];
    __syncthreads();
  }
  double c = scale/sqrt(red[0]);
  #pragma unroll
  for(int itr=0; itr<9; ++itr){
    int e = t + itr*256;
    if(e<tot) dst[e]=(float)(crloc[itr]*c);
  }
}

// ---------------------------------------------------------------- k_weights
__global__ void k_weights(const float* __restrict__ wli, const float* __restrict__ wval,
                          const float* __restrict__ wout, const float* __restrict__ wlo,
                          const float* __restrict__ Wv,
                          unsigned short* __restrict__ WBH, unsigned short* __restrict__ WBL){
  __shared__ float bws[48];
  __shared__ float scs[64];
  __shared__ float As[24];
  int t = threadIdx.x;
  if(t<48){
    const int val_l1[6]={0,0,1,0,1,1};
    int p=t>>3, w=t&7;
    float s=0.f;
    for(int u=0;u<8;u++) s = fmaf(wli[val_l1[p]*8+u], wval[(p*8+u)*8+w], s);
    bws[t]=s;
  }
  {
    const int out_l1[8]={0,0,1,1,0,0,1,1};
    const int out_l3[8]={0,0,0,0,1,1,1,1};
    int p=t>>3, v=t&7;
    float s=0.f;
    for(int u=0;u<8;u++){
      float a=wli[out_l1[p]*8+u];
      for(int w=0;w<8;w++) s = fmaf(wout[((p*8+u)*8+v)*8+w]*a, wlo[out_l3[p]*8+w], s);
    }
    scs[t]=s*0.35355339059327373f;
  }
  __syncthreads();
  if(t<24){
    int p=t/3, i3=t-3*p;
    int vp = (p&1)*3 + i3;
    float s=0.f;
    for(int w=0;w<8;w++) s = fmaf(scs[p*8+w], bws[vp*8+w], s);
    As[t]=s;
  }
  __syncthreads();
  int base = blockIdx.x*960;
  for(int k=0;k<15;k++){
    int cell = base + k*64 + t;
    int f = cell/160, c = cell - f*160;
    float v = 0.f;
    if(f < 88 && c < 132){
      int seg = f/22, off = f - seg*22;
      int even = (off < 9);
      int p = 2*seg + (even?0:1);
      int jo = even ? off : off-9;
      int l1, i, jj;
      if(c < 54){ l1=4; i=c/6; jj=c-6*i; }
      else { int cc=c-54; l1=6; i=cc/6; jj=cc-6*i; }
      if(even){
        if(l1==4 && jj==0)      v = As[p*3+0]*Wv[i*9+jo];
        else if(l1==4)          v = As[p*3+1]*Wv[81+(i*5+jj-1)*9+jo];
        else if(jj>=1)          v = As[p*3+2]*Wv[486+(i*5+jj-1)*9+jo];
      } else {
        if(l1==4 && jj>=1)      v = As[p*3+0]*Wv[1071+(i*5+jj-1)*13+jo];
        else if(l1==6 && jj==0) v = As[p*3+1]*Wv[1656+i*13+jo];
        else if(l1==6)          v = As[p*3+2]*Wv[1825+(i*5+jj-1)*13+jo];
      }
    } else if(f==88 && c==132){
      v = 1.0f;
    }
    unsigned short h = f2bf(v);
    WBH[cell] = h;
    WBL[cell] = f2bf(v - bf2f(h));
  }
}

// ---------------------------------------------------------------- k_prep (MFMA)
// grid 1024 x 128 (2 waves): block = (panel, m-tile) -> 16 points.
__launch_bounds__(128)
__global__ void k_prep(const float* __restrict__ feat, const float* __restrict__ sh,
                       const float* __restrict__ log_s, const float* __restrict__ pos_w,
                       const float* __restrict__ pos_b,
                       const unsigned short* __restrict__ WBH,
                       const unsigned short* __restrict__ WBL,
                       unsigned short* __restrict__ Kgh, unsigned short* __restrict__ Kgl,
                       unsigned short* __restrict__ Vg){
  __shared__ __align__(16) unsigned int Pbuf[16*164];
  __shared__ unsigned int Po[96*17];
  __shared__ float epbs[16];
  int tid = threadIdx.x;
  int w2 = tid >> 6, lane = tid & 63;
  int lm = lane & 15, quad = lane >> 4;
  int seg = w2*4 + quad;
  int panel = blockIdx.x >> 2, mt = blockIdx.x & 3;
  int idxp = panel*64 + mt*16 + lm;
  int n = idxp & (NN-1);
  const float* fp = feat + (size_t)idxp*22;
  const float* shp = sh + n*6;
  float f[22];
  #pragma unroll
  for(int c=0;c<22;c++) f[c]=fp[c];
  float y[6];
  #pragma unroll
  for(int j=0;j<6;j++) y[j]=shp[j];
  if(tid<16){
    float pb = pos_b[0];
    #pragma unroll
    for(int j=0;j<6;j++) pb = fmaf(y[j], pos_w[j], pb);
    epbs[lm] = __expf(pb);
    float n4=0.f, n6=0.f;
    #pragma unroll
    for(int c=0;c<9;c++) n4 += f[c]*f[c];
    #pragma unroll
    for(int c=9;c<22;c++) n6 += f[c]*f[c];
    n4 = fmaxf(sqrtf(n4), 1e-12f);
    n6 = fmaxf(sqrtf(n6), 1e-12f);
    float s4 = __expf(log_s[0]), s6 = __expf(log_s[1]);
    float a4 = sqrtf(s4)/n4, a6 = sqrtf(s6)/n6;
    unsigned short* kph = Kgh + (size_t)idxp*32;
    unsigned short* kpl = Kgl + (size_t)idxp*32;
    #pragma unroll
    for(int c=0;c<22;c++){
      float qv = f[c] * (c<9 ? a4 : a6);
      unsigned short h = f2bf(qv);
      kph[c]=h; kpl[c]=f2bf(qv - bf2f(h));
    }
    #pragma unroll
    for(int c=22;c<32;c++){ kph[c]=0; kpl[c]=0; }
  }
  #pragma unroll
  for(int j4=0;j4<5;j4++){
    u32x4 wv;
    #pragma unroll
    for(int e=0;e<4;e++){
      int c = seg*20 + j4*4 + e;
      float pv;
      if(c<54){ int i=c/6, jj=c-6*i; pv = f[i]*y[jj]; }
      else if(c<132){ int cc=c-54; int i=cc/6, jj=cc-6*i; pv = f[9+i]*y[jj]; }
      else if(c==132) pv = 1.0f;
      else pv = 0.0f;
      wv[e] = pk2r(pv);
    }
    *(u32x4*)&Pbuf[lm*164 + seg*20 + j4*4] = wv;
  }
  __syncthreads();
  f32x4 acc[3];
  #pragma unroll
  for(int ft=0;ft<3;ft++)
    #pragma unroll
    for(int i=0;i<4;i++) acc[ft][i]=0.f;
  for(int kc=0;kc<5;kc++){
    const u32x4* ap = (const u32x4*)&Pbuf[lm*164 + kc*32 + quad*8];
    s16x8 Ah, Al;
    unpk(ap[0], ap[1], Ah, Al);
    #pragma unroll
    for(int ft=0;ft<3;ft++){
      int ftg = w2*3 + ft;
      size_t bo = (size_t)(ftg*16+lm)*160 + kc*32 + quad*8;
      s16x8 Bh = *(const s16x8*)(WBH + bo);
      s16x8 Bl = *(const s16x8*)(WBL + bo);
      f32x4 a = acc[ft];
      a = __builtin_amdgcn_mfma_f32_16x16x32_bf16(Al, Bl, a, 0,0,0);
      a = __builtin_amdgcn_mfma_f32_16x16x32_bf16(Al, Bh, a, 0,0,0);
      a = __builtin_amdgcn_mfma_f32_16x16x32_bf16(Ah, Bl, a, 0,0,0);
      a = __builtin_amdgcn_mfma_f32_16x16x32_bf16(Ah, Bh, a, 0,0,0);
      acc[ft] = a;
    }
  }
  #pragma unroll
  for(int r=0;r<4;r++){
    float e = epbs[quad*4 + r];
    #pragma unroll
    for(int ft=0;ft<3;ft++){
      int ftg = w2*3 + ft;
      Po[(ftg*16+lm)*17 + quad*4 + r] = (unsigned)f2h(acc[ft][r]*e);
    }
  }
  __syncthreads();
  unsigned int* vO32 = (unsigned int*)(Vg + (size_t)panel*96*64);
  #pragma unroll
  for(int wv=0; wv<6; wv++){
    int idx2 = wv*128 + tid;
    int g = idx2 >> 3, j = idx2 & 7;
    unsigned lo = Po[g*17 + 2*j] & 0xFFFFu;
    unsigned hi = Po[g*17 + 2*j + 1] & 0xFFFFu;
    vO32[g*32 + mt*8 + j] = lo | (hi<<16);
  }
}

// ---------------------------------------------------------------- k_attn
// grid 1024 = 4b(fast) x 4kh x 64qb; block 256 (4 waves), BM=64, 16 panels,
// 2 blocks/CU with 256-VGPR budget (__launch_bounds__(256,2)) so the
// EXPLICIT K+V register double-buffers do not spill (R13's failure mode).
// Prefetch for iter i+1 is issued before iter i's single barrier; Es is
// double-buffered so one lgkm-only barrier per iter suffices (WAR separated
// by the intervening barrier). S^T split-3 bf16 (A=K,B=Q); E,V fp16.
#define EST 72
__launch_bounds__(256, 2)
__global__ void k_attn(const unsigned short* __restrict__ Kgh,
                       const unsigned short* __restrict__ Kgl,
                       const unsigned short* __restrict__ Vg,
                       float* __restrict__ ctx0){
  __shared__ __align__(16) unsigned short Es[2][64*EST];   // 18432 B
  int tid = threadIdx.x;
  int lane = tid & 63, w = tid >> 6;
  int lm = lane & 15, quad = lane >> 4;
  int blk = blockIdx.x;
  int b = blk & 3, kh = (blk>>2)&3, qb = blk >> 4;   // qb 0..63
  int qrow0 = qb * 64;
  const unsigned short* KhB = Kgh + (size_t)b*NN*32;
  const unsigned short* KlB = Kgl + (size_t)b*NN*32;
  const unsigned short* VB  = Vg  + (size_t)b*64*96*64;
  float* ctx = ctx0 + (size_t)kh*CTXS + (size_t)b*NN*96;

  int sq = w & 1;    // q-tile pair {2sq,2sq+1}
  int sk = w >> 1;   // S k-tile pair {2sk,2sk+1}; PV f-group {3sk..3sk+2}

  s16x8 qh[2], ql[2];
  #pragma unroll
  for(int q2=0;q2<2;q2++){
    size_t ro = (size_t)(qrow0 + (2*sq+q2)*16 + lm)*32 + (size_t)quad*8;
    qh[q2] = *(const s16x8*)(KhB + ro);
    ql[q2] = *(const s16x8*)(KlB + ro);
  }
  f32x4 acc[2][3];
  #pragma unroll
  for(int q2=0;q2<2;q2++)
    #pragma unroll
    for(int ft=0;ft<3;ft++)
      #pragma unroll
      for(int i=0;i<4;i++) acc[q2][ft][i]=0.f;

  s16x8 kfh[2][2], kfl[2][2];   // [buf][k2]
  f16x8 vv[2][2][3];            // [buf][ks][ft]
  {
    int key0 = (kh*16)*64;
    #pragma unroll
    for(int k2=0;k2<2;k2++){
      size_t ko = (size_t)(key0 + (2*sk+k2)*16 + lm)*32 + (size_t)quad*8;
      kfh[0][k2] = *(const s16x8*)(KhB + ko);
      kfl[0][k2] = *(const s16x8*)(KlB + ko);
    }
    #pragma unroll
    for(int ks=0;ks<2;ks++)
      #pragma unroll
      for(int ft=0;ft<3;ft++){
        size_t vo = (size_t)(kh*16)*96*64 + (size_t)((3*sk+ft)*16+lm)*64 + ks*32 + quad*8;
        vv[0][ks][ft] = *(const f16x8*)(VB + vo);
      }
  }

  #pragma unroll 2
  for(int it=0; it<16; ++it){
    int cur = it&1, nxt = cur^1;
    int panel = kh*16 + it;
    // prefetch K,V for iter it+1 (consumed next iteration; loads stay in
    // flight across the lgkm-only barrier below)
    if(it<15){
      int key0n = (panel+1)*64;
      #pragma unroll
      for(int k2=0;k2<2;k2++){
        size_t ko = (size_t)(key0n + (2*sk+k2)*16 + lm)*32 + (size_t)quad*8;
        kfh[nxt][k2] = *(const s16x8*)(KhB + ko);
        kfl[nxt][k2] = *(const s16x8*)(KlB + ko);
      }
      #pragma unroll
      for(int ks=0;ks<2;ks++)
        #pragma unroll
        for(int ft=0;ft<3;ft++){
          size_t vo = (size_t)(panel+1)*96*64 + (size_t)((3*sk+ft)*16+lm)*64 + ks*32 + quad*8;
          vv[nxt][ks][ft] = *(const f16x8*)(VB + vo);
        }
    }
    // S^T (A=K, B=Q) on current K regs (already resident -> no memory wait)
    unsigned p01[2][2], p23[2][2];
    #pragma unroll
    for(int k2=0;k2<2;k2++)
      #pragma unroll
      for(int q2=0;q2<2;q2++){
        f32x4 s = {0.f,0.f,0.f,0.f};
        s = __builtin_amdgcn_mfma_f32_16x16x32_bf16(kfl[cur][k2], qh[q2], s, 0,0,0);
        s = __builtin_amdgcn_mfma_f32_16x16x32_bf16(kfh[cur][k2], ql[q2], s, 0,0,0);
        s = __builtin_amdgcn_mfma_f32_16x16x32_bf16(kfh[cur][k2], qh[q2], s, 0,0,0);
        p01[k2][q2] = (unsigned)f2h(__expf(s[0])) | ((unsigned)f2h(__expf(s[1]))<<16);
        p23[k2][q2] = (unsigned)f2h(__expf(s[2])) | ((unsigned)f2h(__expf(s[3]))<<16);
      }
    // E write to buffer cur
    #pragma unroll
    for(int k2=0;k2<2;k2++)
      #pragma unroll
      for(int q2=0;q2<2;q2++){
        int row = (2*sq+q2)*16 + lm;
        int key = (2*sk+k2)*16 + quad*4;
        *(u32x2*)&Es[cur][row*EST + key] = (u32x2){p01[k2][q2], p23[k2][q2]};
      }
    barrier_lds();   // single barrier: Es[cur] visible; prefetches in flight
    // PV from Es[cur] + V regs (resident)
    #pragma unroll
    for(int ks=0;ks<2;ks++){
      #pragma unroll
      for(int q2=0;q2<2;q2++){
        f16x8 e = *(const f16x8*)&Es[cur][((2*sq+q2)*16 + lm)*EST + ks*32 + quad*8];
        #pragma unroll
        for(int ft=0;ft<3;ft++)
          acc[q2][ft] = __builtin_amdgcn_mfma_f32_16x16x32_f16(e, vv[cur][ks][ft], acc[q2][ft], 0,0,0);
      }
    }
  }
  #pragma unroll
  for(int q2=0;q2<2;q2++){
    #pragma unroll
    for(int ft=0;ft<3;ft++){
      int col = (3*sk+ft)*16 + lm;
      #pragma unroll
      for(int r=0;r<4;r++){
        int row = qrow0 + (2*sq+q2)*16 + quad*4 + r;
        ctx[(size_t)row*96 + col] = acc[q2][ft][r];
      }
    }
  }
}

// ---------------------------------------------------------------- k_out
// grid 512 x 256: block = (64 points, typ): typ0 -> d4 paths, typ1 -> d6.
__launch_bounds__(256, 2)
__global__ void k_out(const float* __restrict__ feat, const float* __restrict__ ctxA,
                      const float* __restrict__ w3jout, float* __restrict__ out){
  __shared__ float gbuf[64*45];
  __shared__ float fbuf[64*24];
  __shared__ float dls[4*64*13];
  __shared__ float inv[64];
  int tid = threadIdx.x;
  int typ = blockIdx.x & 1;
  int n0 = (blockIdx.x>>1)*64;
  int gc0 = typ*44;
  for(int i=tid;i<64*44;i+=256){
    int pt=i/44, c=i-pt*44;
    const float* base = ctxA + (size_t)(n0+pt)*96 + gc0 + c;
    gbuf[pt*45+c] = base[0]+base[CTXS]+base[2*CTXS]+base[3*CTXS];
  }
  for(int i=tid;i<64*22;i+=256){
    int pt=i/22, c=i-pt*22;
    fbuf[pt*24+c] = feat[(size_t)(n0+pt)*22+c];
  }
  if(tid<64){
    const float* bd = ctxA + (size_t)(n0+tid)*96 + 88;
    inv[tid] = 1.0f/(bd[0]+bd[CTXS]+bd[2*CTXS]+bd[3*CTXS]);
  }
  __syncthreads();
  int lane = tid&63, w = tid>>6;
  float fR[13], gR[13], d[13];
  {
    int FB = (w&2)?9:0;
    int fn = (w&2)?13:9;
    #pragma unroll 13
    for(int i=0;i<13;i++) fR[i] = (i<fn) ? fbuf[lane*24 + FB + i] : 0.f;
    int GBl = (w==0)?0:(w==1)?9:(w==2)?22:31;
    int jn = (w&1)?13:9;
    #pragma unroll 13
    for(int j=0;j<13;j++) gR[j] = (j<jn) ? gbuf[lane*45 + GBl + j] : 0.f;
  }
  #pragma unroll 13
  for(int k=0;k<13;k++) d[k]=0.f;

#define PATHR(ID,JD,KD,WO) \
  _Pragma("unroll") \
  for(int i=0;i<(ID);i++){ float fv=fR[i]; \
    _Pragma("unroll") \
    for(int j=0;j<(JD);j++){ float val=fv*gR[j]; \
      const float* wp = w3jout + (WO) + (i*(JD)+j)*(KD); \
      _Pragma("unroll") \
      for(int k=0;k<(KD);k++) d[k] = fmaf(val, wp[k], d[k]); } }

  int pcase = typ*4 + w;
  switch(pcase){
    case 0: PATHR(9,9,9, 0)       break;
    case 1: PATHR(9,13,9, 729)    break;
    case 2: PATHR(13,9,9, 1782)   break;
    case 3: PATHR(13,13,9, 2835)  break;
    case 4: PATHR(9,9,13, 4356)   break;
    case 5: PATHR(9,13,13, 5409)  break;
    case 6: PATHR(13,9,13, 6930)  break;
    default:PATHR(13,13,13, 8451) break;
  }
#undef PATHR
  {
    float* dp = &dls[(w*64+lane)*13];
    #pragma unroll 13
    for(int k=0;k<13;k++) dp[k]=d[k];
  }
  __syncthreads();
  {
    int KD = typ?13:9;
    int kb = typ?9:0;
    int pt = tid&63, kc = tid>>6;
    float iv = inv[pt];
    #pragma unroll
    for(int e=0;e<4;e++){
      int k = kc*4+e;
      if(k<KD){
        float s = dls[(0*64+pt)*13+k] + dls[(1*64+pt)*13+k]
                + dls[(2*64+pt)*13+k] + dls[(3*64+pt)*13+k];
        out[(size_t)(n0+pt)*22 + kb + k] = s*iv;
      }
    }
  }
}

// ---------------------------------------------------------------- launch
extern "C" void kernel_launch(void* const* d_in, const int* in_sizes, int n_in,
                              void* d_out, int out_size, void* d_ws, size_t ws_size,
                              hipStream_t stream){
  (void)in_sizes; (void)n_in; (void)out_size; (void)ws_size;
  const float* feat =(const float*)d_in[0];
  const float* sh   =(const float*)d_in[1];
  const float* log_s=(const float*)d_in[2];
  const float* pos_w=(const float*)d_in[3];
  const float* pos_b=(const float*)d_in[4];
  const float* wli  =(const float*)d_in[5];
  const float* wval =(const float*)d_in[6];
  const float* wout =(const float*)d_in[7];
  const float* wlo  =(const float*)d_in[8];
  float* outp=(float*)d_out;
  float* wsf=(float*)d_ws;

  unsigned short* Kgh=(unsigned short*)((char*)d_ws + OFFB_KGH);
  unsigned short* Kgl=(unsigned short*)((char*)d_ws + OFFB_KGL);
  unsigned short* Vg =(unsigned short*)((char*)d_ws + OFFB_VG);
  unsigned short* WBH=(unsigned short*)((char*)d_ws + OFFB_WBH);
  unsigned short* WBL=(unsigned short*)((char*)d_ws + OFFB_WBL);

  hipLaunchKernelGGL(k_tab, dim3(14), dim3(256), 0, stream,
                     wsf+OFF_W3JVAL, wsf+OFF_W3JOUT);
  hipLaunchKernelGGL(k_weights, dim3(16), dim3(64), 0, stream,
                     wli, wval, wout, wlo, wsf+OFF_W3JVAL, WBH, WBL);
  hipLaunchKernelGGL(k_prep, dim3(1024), dim3(128), 0, stream,
                     feat, sh, log_s, pos_w, pos_b, WBH, WBL,
                     Kgh, Kgl, Vg);
  hipLaunchKernelGGL(k_attn, dim3(1024), dim3(256), 0, stream,
                     Kgh, Kgl, Vg, wsf+OFF_CTX0);
  hipLaunchKernelGGL(k_out, dim3(512), dim3(256), 0, stream,
                     feat, wsf+OFF_CTX0, wsf+OFF_W3JOUT, outp);
}

// Round 19
// 260.903 us; speedup vs baseline: 1.1635x; 1.1635x over previous
//
#include <hip/hip_runtime.h>
#include <cmath>

#define NN 4096
#define BB 4
#define CCH 8

// ---- workspace float offsets
#define OFF_W3JVAL 0         // 2670 (pad 2688)
#define OFF_W3JOUT 2688      // 10648 -> 13336 (pad 13440)
#define OFF_CTX0   13568     // 4 partials x 4*4096*96 floats -> ends 6305024 fl
#define CTXS       1572864
// ---- byte offsets, 16B aligned (after ctx: 6305024*4 = 25220096)
#define OFFB_KGH   25220096ULL   // u16[4*4096*32] = 1048576 B
#define OFFB_KGL   26268672ULL
#define OFFB_VG    27317248ULL   // u16[4*64*96*64] fp16 = 3145728 B
#define OFFB_WBH   30462976ULL   // u16[96*160] = 30720 B
#define OFFB_WBL   30493696ULL   // end 30524416

typedef short s16x8 __attribute__((ext_vector_type(8)));
typedef _Float16 f16x8 __attribute__((ext_vector_type(8)));
typedef float f32x4 __attribute__((ext_vector_type(4)));
typedef unsigned int u32x4 __attribute__((ext_vector_type(4)));
typedef unsigned int u32x2 __attribute__((ext_vector_type(2)));

static __device__ __forceinline__ unsigned short f2bf(float x){
  unsigned u = __float_as_uint(x);
  return (unsigned short)((u + 0x7FFFu + ((u >> 16) & 1u)) >> 16);
}
static __device__ __forceinline__ float bf2f(unsigned short h){
  return __uint_as_float(((unsigned)h) << 16);
}
static __device__ __forceinline__ unsigned pk2r(float v){
  unsigned short h = f2bf(v);
  unsigned short l = f2bf(v - bf2f(h));
  return ((unsigned)l << 16) | (unsigned)h;
}
static __device__ __forceinline__ unsigned short f2h(float x){
  return __builtin_bit_cast(unsigned short, (_Float16)x);
}
static __device__ __forceinline__ void unpk(u32x4 a, u32x4 b, s16x8& h, s16x8& l){
  u32x4 hw = { __builtin_amdgcn_perm(a[1],a[0],0x05040100u),
               __builtin_amdgcn_perm(a[3],a[2],0x05040100u),
               __builtin_amdgcn_perm(b[1],b[0],0x05040100u),
               __builtin_amdgcn_perm(b[3],b[2],0x05040100u)};
  u32x4 lw = { __builtin_amdgcn_perm(a[1],a[0],0x07060302u),
               __builtin_amdgcn_perm(a[3],a[2],0x07060302u),
               __builtin_amdgcn_perm(b[1],b[0],0x07060302u),
               __builtin_amdgcn_perm(b[3],b[2],0x07060302u)};
  h = __builtin_bit_cast(s16x8, hw);
  l = __builtin_bit_cast(s16x8, lw);
}
// barrier ordering LDS only: global loads stay in flight (no vmcnt drain).
static __device__ __forceinline__ void barrier_lds(){
  __asm__ volatile("s_waitcnt lgkmcnt(0)\n\ts_barrier" ::: "memory");
}

// ---------------------------------------------------------------- k_tab
// Wigner-3j builder, grid 14 x 256. Sparse-Q contraction (<=8 terms/element).
// R19: compact code — unroll-1 loops, fp32 contraction (CG phase stays fp64
// for factorial range; Cc stored fp32), self-owned-element rescale. Shrinks
// i-cache footprint ~10x (R18's 182 KB instruction fetch was the stall).
static __device__ __forceinline__ void qentf(int l, int r, int c, float& re, float& im){
  re=0.f; im=0.f;
  float s = ((l&3)==2)? -1.f : 1.f;
  const float rs2 = 0.70710678118654752440f;
  if(r < l){
    if(c == 2*l - r) re = s*rs2;
    else if(c == r)  im = -s*rs2;
  } else if(r == l){
    if(c == l) re = s;
  } else {
    float sg = ((r-l)&1)? -1.f : 1.f;
    if(c == r) re = s*sg*rs2;
    else if(c == 2*l - r) im = s*sg*rs2;
  }
}
__global__ __launch_bounds__(256) void k_tab(float* __restrict__ Wv, float* __restrict__ Wo){
  __shared__ float Ccf[2197];
  __shared__ float red[256];
  __shared__ double factS[20];
  int t = threadIdx.x;
  int p = blockIdx.x;
  if(t==0){
    double f=1.0; factS[0]=1.0;
    for(int i=1;i<20;i++){ f*=(double)i; factS[i]=f; }
  }
  const int L1[14]={4,4,6,4,6,6, 4,4,6,6,4,4,6,6};
  const int L2[14]={0,2,2,2,0,2, 4,6,4,6,4,6,4,6};
  const int L3[14]={4,4,4,6,6,6, 4,4,4,4,6,6,6,6};
  const int OFF[14]={0,81,486,1071,1656,1825, 0,729,1782,2835,4356,5409,6930,8451};
  int l1=L1[p], l2=L2[p], l3=L3[p];
  int d1=2*l1+1, d2=2*l2+1, d3=2*l3+1;
  int tot = d1*d2*d3;
  float* dst = (p<6) ? (Wv+OFF[p]) : (Wo+OFF[p]);
  float scale = (p<6) ? sqrtf((2.f*l3+1.f)/24.f) : sqrtf((2.f*l3+1.f)/256.f);
  __syncthreads();
  // ---- CG tensor (fp64 math for factorial range; fp32 store)
  #pragma unroll 1
  for(int e=t; e<tot; e+=256){
    int i = e/(d2*d3), rem = e - i*(d2*d3), j = rem/d3, k = rem - j*d3;
    int m1=i-l1, m2=j-l2, m3=k-l3;
    double v=0.0;
    if(m1+m2==m3){
      double pref = sqrt((2.0*l3+1.0)*factS[l3+l1-l2]*factS[l3-l1+l2]*factS[l1+l2-l3]/factS[l1+l2+l3+1]);
      pref *= sqrt(factS[l3+m3]*factS[l3-m3]*factS[l1-m1]*factS[l1+m1]*factS[l2-m2]*factS[l2+m2]);
      double s=0.0;
      #pragma unroll 1
      for(int kk=0; kk<=l1+l2-l3; kk++){
        int dd0=kk, dd1=l1+l2-l3-kk, dd2=l1-m1-kk, dd3=l2+m2-kk, dd4=l3-l2+m1+kk, dd5=l3-l1-m2+kk;
        int mn=dd0;
        if(dd1<mn)mn=dd1; if(dd2<mn)mn=dd2; if(dd3<mn)mn=dd3; if(dd4<mn)mn=dd4; if(dd5<mn)mn=dd5;
        if(mn<0) continue;
        double prod = factS[dd0]*factS[dd1]*factS[dd2]*factS[dd3]*factS[dd4]*factS[dd5];
        s += ((kk&1)? -1.0:1.0)/prod;
      }
      v = pref*s;
    }
    Ccf[e]=(float)v;
  }
  __syncthreads();
  // ---- sparse-Q contraction (fp32), write unscaled, accumulate norm
  float nacc=0.f;
  #pragma unroll 1
  for(int e=t; e<tot; e+=256){
    int j = e/(d2*d3), rem = e - j*(d2*d3), l = rem/d3, n = rem - l*d3;
    float re = 0.f;
    #pragma unroll
    for(int ii=0; ii<2; ii++){
      int i = ii ? (2*l1 - j) : j;
      float q1r,q1i; qentf(l1,i,j,q1r,q1i);
      if(ii && i==j){ q1r=0.f; q1i=0.f; }
      #pragma unroll
      for(int kk=0; kk<2; kk++){
        int k = kk ? (2*l2 - l) : l;
        float q2r,q2i; qentf(l2,k,l,q2r,q2i);
        if(kk && k==l){ q2r=0.f; q2i=0.f; }
        float ar = q1r*q2r - q1i*q2i;
        float ai = q1r*q2i + q1i*q2r;
        #pragma unroll
        for(int mm=0; mm<2; mm++){
          int m = mm ? (2*l3 - n) : n;
          float q3r,q3i; qentf(l3,m,n,q3r,q3i);
          if(mm && m==n){ q3r=0.f; q3i=0.f; }
          float coef = ar*q3r + ai*q3i;   // Re( (q1*q2) * conj(q3) )
          re = fmaf(coef, Ccf[(i*d2+k)*d3+m], re);
        }
      }
    }
    dst[e]=re;
    nacc = fmaf(re,re,nacc);
  }
  red[t]=nacc;
  __syncthreads();
  #pragma unroll 1
  for(int s=128;s>0;s>>=1){
    if(t<s) red[t]+=red[t+s];
    __syncthreads();
  }
  float c = scale/sqrtf(red[0]);
  // each thread rescales the elements it wrote (own-thread RAW on global)
  #pragma unroll 1
  for(int e=t; e<tot; e+=256) dst[e]*=c;
}

// ---------------------------------------------------------------- k_weights
__global__ void k_weights(const float* __restrict__ wli, const float* __restrict__ wval,
                          const float* __restrict__ wout, const float* __restrict__ wlo,
                          const float* __restrict__ Wv,
                          unsigned short* __restrict__ WBH, unsigned short* __restrict__ WBL){
  __shared__ float bws[48];
  __shared__ float scs[64];
  __shared__ float As[24];
  int t = threadIdx.x;
  if(t<48){
    const int val_l1[6]={0,0,1,0,1,1};
    int p=t>>3, w=t&7;
    float s=0.f;
    for(int u=0;u<8;u++) s = fmaf(wli[val_l1[p]*8+u], wval[(p*8+u)*8+w], s);
    bws[t]=s;
  }
  {
    const int out_l1[8]={0,0,1,1,0,0,1,1};
    const int out_l3[8]={0,0,0,0,1,1,1,1};
    int p=t>>3, v=t&7;
    float s=0.f;
    for(int u=0;u<8;u++){
      float a=wli[out_l1[p]*8+u];
      for(int w=0;w<8;w++) s = fmaf(wout[((p*8+u)*8+v)*8+w]*a, wlo[out_l3[p]*8+w], s);
    }
    scs[t]=s*0.35355339059327373f;
  }
  __syncthreads();
  if(t<24){
    int p=t/3, i3=t-3*p;
    int vp = (p&1)*3 + i3;
    float s=0.f;
    for(int w=0;w<8;w++) s = fmaf(scs[p*8+w], bws[vp*8+w], s);
    As[t]=s;
  }
  __syncthreads();
  int base = blockIdx.x*960;
  for(int k=0;k<15;k++){
    int cell = base + k*64 + t;
    int f = cell/160, c = cell - f*160;
    float v = 0.f;
    if(f < 88 && c < 132){
      int seg = f/22, off = f - seg*22;
      int even = (off < 9);
      int p = 2*seg + (even?0:1);
      int jo = even ? off : off-9;
      int l1, i, jj;
      if(c < 54){ l1=4; i=c/6; jj=c-6*i; }
      else { int cc=c-54; l1=6; i=cc/6; jj=cc-6*i; }
      if(even){
        if(l1==4 && jj==0)      v = As[p*3+0]*Wv[i*9+jo];
        else if(l1==4)          v = As[p*3+1]*Wv[81+(i*5+jj-1)*9+jo];
        else if(jj>=1)          v = As[p*3+2]*Wv[486+(i*5+jj-1)*9+jo];
      } else {
        if(l1==4 && jj>=1)      v = As[p*3+0]*Wv[1071+(i*5+jj-1)*13+jo];
        else if(l1==6 && jj==0) v = As[p*3+1]*Wv[1656+i*13+jo];
        else if(l1==6)          v = As[p*3+2]*Wv[1825+(i*5+jj-1)*13+jo];
      }
    } else if(f==88 && c==132){
      v = 1.0f;
    }
    unsigned short h = f2bf(v);
    WBH[cell] = h;
    WBL[cell] = f2bf(v - bf2f(h));
  }
}

// ---------------------------------------------------------------- k_prep (MFMA)
// grid 1024 x 128 (2 waves): block = (panel, m-tile) -> 16 points.
__launch_bounds__(128)
__global__ void k_prep(const float* __restrict__ feat, const float* __restrict__ sh,
                       const float* __restrict__ log_s, const float* __restrict__ pos_w,
                       const float* __restrict__ pos_b,
                       const unsigned short* __restrict__ WBH,
                       const unsigned short* __restrict__ WBL,
                       unsigned short* __restrict__ Kgh, unsigned short* __restrict__ Kgl,
                       unsigned short* __restrict__ Vg){
  __shared__ __align__(16) unsigned int Pbuf[16*164];
  __shared__ unsigned int Po[96*17];
  __shared__ float epbs[16];
  int tid = threadIdx.x;
  int w2 = tid >> 6, lane = tid & 63;
  int lm = lane & 15, quad = lane >> 4;
  int seg = w2*4 + quad;
  int panel = blockIdx.x >> 2, mt = blockIdx.x & 3;
  int idxp = panel*64 + mt*16 + lm;
  int n = idxp & (NN-1);
  const float* fp = feat + (size_t)idxp*22;
  const float* shp = sh + n*6;
  float f[22];
  #pragma unroll
  for(int c=0;c<22;c++) f[c]=fp[c];
  float y[6];
  #pragma unroll
  for(int j=0;j<6;j++) y[j]=shp[j];
  if(tid<16){
    float pb = pos_b[0];
    #pragma unroll
    for(int j=0;j<6;j++) pb = fmaf(y[j], pos_w[j], pb);
    epbs[lm] = __expf(pb);
    float n4=0.f, n6=0.f;
    #pragma unroll
    for(int c=0;c<9;c++) n4 += f[c]*f[c];
    #pragma unroll
    for(int c=9;c<22;c++) n6 += f[c]*f[c];
    n4 = fmaxf(sqrtf(n4), 1e-12f);
    n6 = fmaxf(sqrtf(n6), 1e-12f);
    float s4 = __expf(log_s[0]), s6 = __expf(log_s[1]);
    float a4 = sqrtf(s4)/n4, a6 = sqrtf(s6)/n6;
    unsigned short* kph = Kgh + (size_t)idxp*32;
    unsigned short* kpl = Kgl + (size_t)idxp*32;
    #pragma unroll
    for(int c=0;c<22;c++){
      float qv = f[c] * (c<9 ? a4 : a6);
      unsigned short h = f2bf(qv);
      kph[c]=h; kpl[c]=f2bf(qv - bf2f(h));
    }
    #pragma unroll
    for(int c=22;c<32;c++){ kph[c]=0; kpl[c]=0; }
  }
  #pragma unroll
  for(int j4=0;j4<5;j4++){
    u32x4 wv;
    #pragma unroll
    for(int e=0;e<4;e++){
      int c = seg*20 + j4*4 + e;
      float pv;
      if(c<54){ int i=c/6, jj=c-6*i; pv = f[i]*y[jj]; }
      else if(c<132){ int cc=c-54; int i=cc/6, jj=cc-6*i; pv = f[9+i]*y[jj]; }
      else if(c==132) pv = 1.0f;
      else pv = 0.0f;
      wv[e] = pk2r(pv);
    }
    *(u32x4*)&Pbuf[lm*164 + seg*20 + j4*4] = wv;
  }
  __syncthreads();
  f32x4 acc[3];
  #pragma unroll
  for(int ft=0;ft<3;ft++)
    #pragma unroll
    for(int i=0;i<4;i++) acc[ft][i]=0.f;
  for(int kc=0;kc<5;kc++){
    const u32x4* ap = (const u32x4*)&Pbuf[lm*164 + kc*32 + quad*8];
    s16x8 Ah, Al;
    unpk(ap[0], ap[1], Ah, Al);
    #pragma unroll
    for(int ft=0;ft<3;ft++){
      int ftg = w2*3 + ft;
      size_t bo = (size_t)(ftg*16+lm)*160 + kc*32 + quad*8;
      s16x8 Bh = *(const s16x8*)(WBH + bo);
      s16x8 Bl = *(const s16x8*)(WBL + bo);
      f32x4 a = acc[ft];
      a = __builtin_amdgcn_mfma_f32_16x16x32_bf16(Al, Bl, a, 0,0,0);
      a = __builtin_amdgcn_mfma_f32_16x16x32_bf16(Al, Bh, a, 0,0,0);
      a = __builtin_amdgcn_mfma_f32_16x16x32_bf16(Ah, Bl, a, 0,0,0);
      a = __builtin_amdgcn_mfma_f32_16x16x32_bf16(Ah, Bh, a, 0,0,0);
      acc[ft] = a;
    }
  }
  #pragma unroll
  for(int r=0;r<4;r++){
    float e = epbs[quad*4 + r];
    #pragma unroll
    for(int ft=0;ft<3;ft++){
      int ftg = w2*3 + ft;
      Po[(ftg*16+lm)*17 + quad*4 + r] = (unsigned)f2h(acc[ft][r]*e);
    }
  }
  __syncthreads();
  unsigned int* vO32 = (unsigned int*)(Vg + (size_t)panel*96*64);
  #pragma unroll
  for(int wv=0; wv<6; wv++){
    int idx2 = wv*128 + tid;
    int g = idx2 >> 3, j = idx2 & 7;
    unsigned lo = Po[g*17 + 2*j] & 0xFFFFu;
    unsigned hi = Po[g*17 + 2*j + 1] & 0xFFFFu;
    vO32[g*32 + mt*8 + j] = lo | (hi<<16);
  }
}

// ---------------------------------------------------------------- k_attn
// Exact R12/R17 structure (measured 66.8-67.5us three times): grid 512 =
// 4b(fast) x 4kh x 32qb; block 512 (8 waves), BM=128, 16 panels, 2 blocks/CU.
// S^T split-3 bf16 (A=K,B=Q); E,V fp16 -> 1 MFMA per PV tile; lgkm-only
// barriers keep K/V global loads in flight.
#define EST 72
__launch_bounds__(512, 4)
__global__ void k_attn(const unsigned short* __restrict__ Kgh,
                       const unsigned short* __restrict__ Kgl,
                       const unsigned short* __restrict__ Vg,
                       float* __restrict__ ctx0){
  __shared__ __align__(16) unsigned short Es[128*EST];   // 18432 B
  int tid = threadIdx.x;
  int lane = tid & 63, w = tid >> 6;
  int lm = lane & 15, quad = lane >> 4;
  int blk = blockIdx.x;
  int b = blk & 3, kh = (blk>>2)&3, qb = blk >> 4;   // qb 0..31
  int qrow0 = qb * 128;
  const unsigned short* KhB = Kgh + (size_t)b*NN*32;
  const unsigned short* KlB = Kgl + (size_t)b*NN*32;
  const unsigned short* VB  = Vg  + (size_t)b*64*96*64;
  float* ctx = ctx0 + (size_t)kh*CTXS + (size_t)b*NN*96;

  int sq = w & 3;
  int sk = w >> 2;

  s16x8 qh[2], ql[2];
  #pragma unroll
  for(int q2=0;q2<2;q2++){
    size_t ro = (size_t)(qrow0 + (2*sq+q2)*16 + lm)*32 + (size_t)quad*8;
    qh[q2] = *(const s16x8*)(KhB + ro);
    ql[q2] = *(const s16x8*)(KlB + ro);
  }
  f32x4 acc[2][3];
  #pragma unroll
  for(int q2=0;q2<2;q2++)
    #pragma unroll
    for(int ft=0;ft<3;ft++)
      #pragma unroll
      for(int i=0;i<4;i++) acc[q2][ft][i]=0.f;

  #pragma unroll 1
  for(int it=0; it<16; ++it){
    int panel = kh*16 + it;
    int key0 = panel*64;
    s16x8 kfh[2], kfl[2];
    #pragma unroll
    for(int k2=0;k2<2;k2++){
      size_t ko = (size_t)(key0 + (2*sk+k2)*16 + lm)*32 + (size_t)quad*8;
      kfh[k2] = *(const s16x8*)(KhB + ko);
      kfl[k2] = *(const s16x8*)(KlB + ko);
    }
    f16x8 vv[2][3];
    #pragma unroll
    for(int ks=0;ks<2;ks++)
      #pragma unroll
      for(int ft=0;ft<3;ft++){
        size_t vo = (size_t)panel*96*64 + (size_t)((3*sk+ft)*16+lm)*64 + ks*32 + quad*8;
        vv[ks][ft] = *(const f16x8*)(VB + vo);
      }
    unsigned p01[2][2], p23[2][2];
    #pragma unroll
    for(int k2=0;k2<2;k2++)
      #pragma unroll
      for(int q2=0;q2<2;q2++){
        f32x4 s = {0.f,0.f,0.f,0.f};
        s = __builtin_amdgcn_mfma_f32_16x16x32_bf16(kfl[k2], qh[q2], s, 0,0,0);
        s = __builtin_amdgcn_mfma_f32_16x16x32_bf16(kfh[k2], ql[q2], s, 0,0,0);
        s = __builtin_amdgcn_mfma_f32_16x16x32_bf16(kfh[k2], qh[q2], s, 0,0,0);
        p01[k2][q2] = (unsigned)f2h(__expf(s[0])) | ((unsigned)f2h(__expf(s[1]))<<16);
        p23[k2][q2] = (unsigned)f2h(__expf(s[2])) | ((unsigned)f2h(__expf(s[3]))<<16);
      }
    barrier_lds();
    #pragma unroll
    for(int k2=0;k2<2;k2++)
      #pragma unroll
      for(int q2=0;q2<2;q2++){
        int row = (2*sq+q2)*16 + lm;
        int key = (2*sk+k2)*16 + quad*4;
        *(u32x2*)&Es[row*EST + key] = (u32x2){p01[k2][q2], p23[k2][q2]};
      }
    barrier_lds();
    #pragma unroll
    for(int ks=0;ks<2;ks++){
      #pragma unroll
      for(int q2=0;q2<2;q2++){
        f16x8 e = *(const f16x8*)&Es[((2*sq+q2)*16 + lm)*EST + ks*32 + quad*8];
        #pragma unroll
        for(int ft=0;ft<3;ft++)
          acc[q2][ft] = __builtin_amdgcn_mfma_f32_16x16x32_f16(e, vv[ks][ft], acc[q2][ft], 0,0,0);
      }
    }
  }
  #pragma unroll
  for(int q2=0;q2<2;q2++){
    #pragma unroll
    for(int ft=0;ft<3;ft++){
      int col = (3*sk+ft)*16 + lm;
      #pragma unroll
      for(int r=0;r<4;r++){
        int row = qrow0 + (2*sq+q2)*16 + quad*4 + r;
        ctx[(size_t)row*96 + col] = acc[q2][ft][r];
      }
    }
  }
}

// ---------------------------------------------------------------- k_out
// grid 512 x 256: block = (64 points, typ): typ0 -> d4 paths, typ1 -> d6.
__launch_bounds__(256, 2)
__global__ void k_out(const float* __restrict__ feat, const float* __restrict__ ctxA,
                      const float* __restrict__ w3jout, float* __restrict__ out){
  __shared__ float gbuf[64*45];
  __shared__ float fbuf[64*24];
  __shared__ float dls[4*64*13];
  __shared__ float inv[64];
  int tid = threadIdx.x;
  int typ = blockIdx.x & 1;
  int n0 = (blockIdx.x>>1)*64;
  int gc0 = typ*44;
  for(int i=tid;i<64*44;i+=256){
    int pt=i/44, c=i-pt*44;
    const float* base = ctxA + (size_t)(n0+pt)*96 + gc0 + c;
    gbuf[pt*45+c] = base[0]+base[CTXS]+base[2*CTXS]+base[3*CTXS];
  }
  for(int i=tid;i<64*22;i+=256){
    int pt=i/22, c=i-pt*22;
    fbuf[pt*24+c] = feat[(size_t)(n0+pt)*22+c];
  }
  if(tid<64){
    const float* bd = ctxA + (size_t)(n0+tid)*96 + 88;
    inv[tid] = 1.0f/(bd[0]+bd[CTXS]+bd[2*CTXS]+bd[3*CTXS]);
  }
  __syncthreads();
  int lane = tid&63, w = tid>>6;
  float fR[13], gR[13], d[13];
  {
    int FB = (w&2)?9:0;
    int fn = (w&2)?13:9;
    #pragma unroll 13
    for(int i=0;i<13;i++) fR[i] = (i<fn) ? fbuf[lane*24 + FB + i] : 0.f;
    int GBl = (w==0)?0:(w==1)?9:(w==2)?22:31;
    int jn = (w&1)?13:9;
    #pragma unroll 13
    for(int j=0;j<13;j++) gR[j] = (j<jn) ? gbuf[lane*45 + GBl + j] : 0.f;
  }
  #pragma unroll 13
  for(int k=0;k<13;k++) d[k]=0.f;

#define PATHR(ID,JD,KD,WO) \
  _Pragma("unroll") \
  for(int i=0;i<(ID);i++){ float fv=fR[i]; \
    _Pragma("unroll") \
    for(int j=0;j<(JD);j++){ float val=fv*gR[j]; \
      const float* wp = w3jout + (WO) + (i*(JD)+j)*(KD); \
      _Pragma("unroll") \
      for(int k=0;k<(KD);k++) d[k] = fmaf(val, wp[k], d[k]); } }

  int pcase = typ*4 + w;
  switch(pcase){
    case 0: PATHR(9,9,9, 0)       break;
    case 1: PATHR(9,13,9, 729)    break;
    case 2: PATHR(13,9,9, 1782)   break;
    case 3: PATHR(13,13,9, 2835)  break;
    case 4: PATHR(9,9,13, 4356)   break;
    case 5: PATHR(9,13,13, 5409)  break;
    case 6: PATHR(13,9,13, 6930)  break;
    default:PATHR(13,13,13, 8451) break;
  }
#undef PATHR
  {
    float* dp = &dls[(w*64+lane)*13];
    #pragma unroll 13
    for(int k=0;k<13;k++) dp[k]=d[k];
  }
  __syncthreads();
  {
    int KD = typ?13:9;
    int kb = typ?9:0;
    int pt = tid&63, kc = tid>>6;
    float iv = inv[pt];
    #pragma unroll
    for(int e=0;e<4;e++){
      int k = kc*4+e;
      if(k<KD){
        float s = dls[(0*64+pt)*13+k] + dls[(1*64+pt)*13+k]
                + dls[(2*64+pt)*13+k] + dls[(3*64+pt)*13+k];
        out[(size_t)(n0+pt)*22 + kb + k] = s*iv;
      }
    }
  }
}

// ---------------------------------------------------------------- launch
extern "C" void kernel_launch(void* const* d_in, const int* in_sizes, int n_in,
                              void* d_out, int out_size, void* d_ws, size_t ws_size,
                              hipStream_t stream){
  (void)in_sizes; (void)n_in; (void)out_size; (void)ws_size;
  const float* feat =(const float*)d_in[0];
  const float* sh   =(const float*)d_in[1];
  const float* log_s=(const float*)d_in[2];
  const float* pos_w=(const float*)d_in[3];
  const float* pos_b=(const float*)d_in[4];
  const float* wli  =(const float*)d_in[5];
  const float* wval =(const float*)d_in[6];
  const float* wout =(const float*)d_in[7];
  const float* wlo  =(const float*)d_in[8];
  float* outp=(float*)d_out;
  float* wsf=(float*)d_ws;

  unsigned short* Kgh=(unsigned short*)((char*)d_ws + OFFB_KGH);
  unsigned short* Kgl=(unsigned short*)((char*)d_ws + OFFB_KGL);
  unsigned short* Vg =(unsigned short*)((char*)d_ws + OFFB_VG);
  unsigned short* WBH=(unsigned short*)((char*)d_ws + OFFB_WBH);
  unsigned short* WBL=(unsigned short*)((char*)d_ws + OFFB_WBL);

  hipLaunchKernelGGL(k_tab, dim3(14), dim3(256), 0, stream,
                     wsf+OFF_W3JVAL, wsf+OFF_W3JOUT);
  hipLaunchKernelGGL(k_weights, dim3(16), dim3(64), 0, stream,
                     wli, wval, wout, wlo, wsf+OFF_W3JVAL, WBH, WBL);
  hipLaunchKernelGGL(k_prep, dim3(1024), dim3(128), 0, stream,
                     feat, sh, log_s, pos_w, pos_b, WBH, WBL,
                     Kgh, Kgl, Vg);
  hipLaunchKernelGGL(k_attn, dim3(512), dim3(512), 0, stream,
                     Kgh, Kgl, Vg, wsf+OFF_CTX0);
  hipLaunchKernelGGL(k_out, dim3(512), dim3(256), 0, stream,
                     feat, wsf+OFF_CTX0, wsf+OFF_W3JOUT, outp);
}

// Round 20
// 214.203 us; speedup vs baseline: 1.4172x; 1.2180x over previous
//
#include <hip/hip_runtime.h>
#include <cmath>

#define NN 4096
#define BB 4
#define CCH 8

// ---- workspace float offsets
#define OFF_W3JVAL 0         // 2670 (pad 2688)
#define OFF_W3JOUT 2688      // 10648 -> 13336 (pad 13440)
#define OFF_CTX0   13568     // 4 partials x 4*4096*96 floats -> ends 6305024 fl
#define CTXS       1572864
// ---- byte offsets, 16B aligned (after ctx: 6305024*4 = 25220096)
#define OFFB_KGH   25220096ULL   // u16[4*4096*32] = 1048576 B
#define OFFB_KGL   26268672ULL
#define OFFB_VG    27317248ULL   // u16[4*64*96*64] fp16 = 3145728 B
#define OFFB_WBH   30462976ULL   // u16[96*160] = 30720 B
#define OFFB_WBL   30493696ULL   // end 30524416

typedef short s16x8 __attribute__((ext_vector_type(8)));
typedef _Float16 f16x8 __attribute__((ext_vector_type(8)));
typedef float f32x4 __attribute__((ext_vector_type(4)));
typedef unsigned int u32x4 __attribute__((ext_vector_type(4)));
typedef unsigned int u32x2 __attribute__((ext_vector_type(2)));

static __device__ __forceinline__ unsigned short f2bf(float x){
  unsigned u = __float_as_uint(x);
  return (unsigned short)((u + 0x7FFFu + ((u >> 16) & 1u)) >> 16);
}
static __device__ __forceinline__ float bf2f(unsigned short h){
  return __uint_as_float(((unsigned)h) << 16);
}
static __device__ __forceinline__ unsigned pk2r(float v){
  unsigned short h = f2bf(v);
  unsigned short l = f2bf(v - bf2f(h));
  return ((unsigned)l << 16) | (unsigned)h;
}
static __device__ __forceinline__ unsigned short f2h(float x){
  return __builtin_bit_cast(unsigned short, (_Float16)x);
}
static __device__ __forceinline__ void unpk(u32x4 a, u32x4 b, s16x8& h, s16x8& l){
  u32x4 hw = { __builtin_amdgcn_perm(a[1],a[0],0x05040100u),
               __builtin_amdgcn_perm(a[3],a[2],0x05040100u),
               __builtin_amdgcn_perm(b[1],b[0],0x05040100u),
               __builtin_amdgcn_perm(b[3],b[2],0x05040100u)};
  u32x4 lw = { __builtin_amdgcn_perm(a[1],a[0],0x07060302u),
               __builtin_amdgcn_perm(a[3],a[2],0x07060302u),
               __builtin_amdgcn_perm(b[1],b[0],0x07060302u),
               __builtin_amdgcn_perm(b[3],b[2],0x07060302u)};
  h = __builtin_bit_cast(s16x8, hw);
  l = __builtin_bit_cast(s16x8, lw);
}
// barrier ordering LDS only: global loads stay in flight (no vmcnt drain).
static __device__ __forceinline__ void barrier_lds(){
  __asm__ volatile("s_waitcnt lgkmcnt(0)\n\ts_barrier" ::: "memory");
}

// ---------------------------------------------------------------- k_tab
// Wigner-3j builder, grid 14 x 256. Sparse-Q contraction (<=8 terms/element),
// compact code (unroll-1), fp32 contraction, self-owned-element rescale.
static __device__ __forceinline__ void qentf(int l, int r, int c, float& re, float& im){
  re=0.f; im=0.f;
  float s = ((l&3)==2)? -1.f : 1.f;
  const float rs2 = 0.70710678118654752440f;
  if(r < l){
    if(c == 2*l - r) re = s*rs2;
    else if(c == r)  im = -s*rs2;
  } else if(r == l){
    if(c == l) re = s;
  } else {
    float sg = ((r-l)&1)? -1.f : 1.f;
    if(c == r) re = s*sg*rs2;
    else if(c == 2*l - r) im = s*sg*rs2;
  }
}
__global__ __launch_bounds__(256) void k_tab(float* __restrict__ Wv, float* __restrict__ Wo){
  __shared__ float Ccf[2197];
  __shared__ float red[256];
  __shared__ double factS[20];
  int t = threadIdx.x;
  int p = blockIdx.x;
  if(t==0){
    double f=1.0; factS[0]=1.0;
    for(int i=1;i<20;i++){ f*=(double)i; factS[i]=f; }
  }
  const int L1[14]={4,4,6,4,6,6, 4,4,6,6,4,4,6,6};
  const int L2[14]={0,2,2,2,0,2, 4,6,4,6,4,6,4,6};
  const int L3[14]={4,4,4,6,6,6, 4,4,4,4,6,6,6,6};
  const int OFF[14]={0,81,486,1071,1656,1825, 0,729,1782,2835,4356,5409,6930,8451};
  int l1=L1[p], l2=L2[p], l3=L3[p];
  int d1=2*l1+1, d2=2*l2+1, d3=2*l3+1;
  int tot = d1*d2*d3;
  float* dst = (p<6) ? (Wv+OFF[p]) : (Wo+OFF[p]);
  float scale = (p<6) ? sqrtf((2.f*l3+1.f)/24.f) : sqrtf((2.f*l3+1.f)/256.f);
  __syncthreads();
  #pragma unroll 1
  for(int e=t; e<tot; e+=256){
    int i = e/(d2*d3), rem = e - i*(d2*d3), j = rem/d3, k = rem - j*d3;
    int m1=i-l1, m2=j-l2, m3=k-l3;
    double v=0.0;
    if(m1+m2==m3){
      double pref = sqrt((2.0*l3+1.0)*factS[l3+l1-l2]*factS[l3-l1+l2]*factS[l1+l2-l3]/factS[l1+l2+l3+1]);
      pref *= sqrt(factS[l3+m3]*factS[l3-m3]*factS[l1-m1]*factS[l1+m1]*factS[l2-m2]*factS[l2+m2]);
      double s=0.0;
      #pragma unroll 1
      for(int kk=0; kk<=l1+l2-l3; kk++){
        int dd0=kk, dd1=l1+l2-l3-kk, dd2=l1-m1-kk, dd3=l2+m2-kk, dd4=l3-l2+m1+kk, dd5=l3-l1-m2+kk;
        int mn=dd0;
        if(dd1<mn)mn=dd1; if(dd2<mn)mn=dd2; if(dd3<mn)mn=dd3; if(dd4<mn)mn=dd4; if(dd5<mn)mn=dd5;
        if(mn<0) continue;
        double prod = factS[dd0]*factS[dd1]*factS[dd2]*factS[dd3]*factS[dd4]*factS[dd5];
        s += ((kk&1)? -1.0:1.0)/prod;
      }
      v = pref*s;
    }
    Ccf[e]=(float)v;
  }
  __syncthreads();
  float nacc=0.f;
  #pragma unroll 1
  for(int e=t; e<tot; e+=256){
    int j = e/(d2*d3), rem = e - j*(d2*d3), l = rem/d3, n = rem - l*d3;
    float re = 0.f;
    #pragma unroll
    for(int ii=0; ii<2; ii++){
      int i = ii ? (2*l1 - j) : j;
      float q1r,q1i; qentf(l1,i,j,q1r,q1i);
      if(ii && i==j){ q1r=0.f; q1i=0.f; }
      #pragma unroll
      for(int kk=0; kk<2; kk++){
        int k = kk ? (2*l2 - l) : l;
        float q2r,q2i; qentf(l2,k,l,q2r,q2i);
        if(kk && k==l){ q2r=0.f; q2i=0.f; }
        float ar = q1r*q2r - q1i*q2i;
        float ai = q1r*q2i + q1i*q2r;
        #pragma unroll
        for(int mm=0; mm<2; mm++){
          int m = mm ? (2*l3 - n) : n;
          float q3r,q3i; qentf(l3,m,n,q3r,q3i);
          if(mm && m==n){ q3r=0.f; q3i=0.f; }
          float coef = ar*q3r + ai*q3i;
          re = fmaf(coef, Ccf[(i*d2+k)*d3+m], re);
        }
      }
    }
    dst[e]=re;
    nacc = fmaf(re,re,nacc);
  }
  red[t]=nacc;
  __syncthreads();
  #pragma unroll 1
  for(int s=128;s>0;s>>=1){
    if(t<s) red[t]+=red[t+s];
    __syncthreads();
  }
  float c = scale/sqrtf(red[0]);
  #pragma unroll 1
  for(int e=t; e<tot; e+=256) dst[e]*=c;
}

// ---------------------------------------------------------------- k_weights
__global__ void k_weights(const float* __restrict__ wli, const float* __restrict__ wval,
                          const float* __restrict__ wout, const float* __restrict__ wlo,
                          const float* __restrict__ Wv,
                          unsigned short* __restrict__ WBH, unsigned short* __restrict__ WBL){
  __shared__ float bws[48];
  __shared__ float scs[64];
  __shared__ float As[24];
  int t = threadIdx.x;
  if(t<48){
    const int val_l1[6]={0,0,1,0,1,1};
    int p=t>>3, w=t&7;
    float s=0.f;
    for(int u=0;u<8;u++) s = fmaf(wli[val_l1[p]*8+u], wval[(p*8+u)*8+w], s);
    bws[t]=s;
  }
  {
    const int out_l1[8]={0,0,1,1,0,0,1,1};
    const int out_l3[8]={0,0,0,0,1,1,1,1};
    int p=t>>3, v=t&7;
    float s=0.f;
    for(int u=0;u<8;u++){
      float a=wli[out_l1[p]*8+u];
      for(int w=0;w<8;w++) s = fmaf(wout[((p*8+u)*8+v)*8+w]*a, wlo[out_l3[p]*8+w], s);
    }
    scs[t]=s*0.35355339059327373f;
  }
  __syncthreads();
  if(t<24){
    int p=t/3, i3=t-3*p;
    int vp = (p&1)*3 + i3;
    float s=0.f;
    for(int w=0;w<8;w++) s = fmaf(scs[p*8+w], bws[vp*8+w], s);
    As[t]=s;
  }
  __syncthreads();
  int base = blockIdx.x*960;
  for(int k=0;k<15;k++){
    int cell = base + k*64 + t;
    int f = cell/160, c = cell - f*160;
    float v = 0.f;
    if(f < 88 && c < 132){
      int seg = f/22, off = f - seg*22;
      int even = (off < 9);
      int p = 2*seg + (even?0:1);
      int jo = even ? off : off-9;
      int l1, i, jj;
      if(c < 54){ l1=4; i=c/6; jj=c-6*i; }
      else { int cc=c-54; l1=6; i=cc/6; jj=cc-6*i; }
      if(even){
        if(l1==4 && jj==0)      v = As[p*3+0]*Wv[i*9+jo];
        else if(l1==4)          v = As[p*3+1]*Wv[81+(i*5+jj-1)*9+jo];
        else if(jj>=1)          v = As[p*3+2]*Wv[486+(i*5+jj-1)*9+jo];
      } else {
        if(l1==4 && jj>=1)      v = As[p*3+0]*Wv[1071+(i*5+jj-1)*13+jo];
        else if(l1==6 && jj==0) v = As[p*3+1]*Wv[1656+i*13+jo];
        else if(l1==6)          v = As[p*3+2]*Wv[1825+(i*5+jj-1)*13+jo];
      }
    } else if(f==88 && c==132){
      v = 1.0f;
    }
    unsigned short h = f2bf(v);
    WBH[cell] = h;
    WBL[cell] = f2bf(v - bf2f(h));
  }
}

// ---------------------------------------------------------------- k_prep (MFMA)
// grid 1024 x 128 (2 waves): block = (panel, m-tile) -> 16 points.
__launch_bounds__(128)
__global__ void k_prep(const float* __restrict__ feat, const float* __restrict__ sh,
                       const float* __restrict__ log_s, const float* __restrict__ pos_w,
                       const float* __restrict__ pos_b,
                       const unsigned short* __restrict__ WBH,
                       const unsigned short* __restrict__ WBL,
                       unsigned short* __restrict__ Kgh, unsigned short* __restrict__ Kgl,
                       unsigned short* __restrict__ Vg){
  __shared__ __align__(16) unsigned int Pbuf[16*164];
  __shared__ unsigned int Po[96*17];
  __shared__ float epbs[16];
  int tid = threadIdx.x;
  int w2 = tid >> 6, lane = tid & 63;
  int lm = lane & 15, quad = lane >> 4;
  int seg = w2*4 + quad;
  int panel = blockIdx.x >> 2, mt = blockIdx.x & 3;
  int idxp = panel*64 + mt*16 + lm;
  int n = idxp & (NN-1);
  const float* fp = feat + (size_t)idxp*22;
  const float* shp = sh + n*6;
  float f[22];
  #pragma unroll
  for(int c=0;c<22;c++) f[c]=fp[c];
  float y[6];
  #pragma unroll
  for(int j=0;j<6;j++) y[j]=shp[j];
  if(tid<16){
    float pb = pos_b[0];
    #pragma unroll
    for(int j=0;j<6;j++) pb = fmaf(y[j], pos_w[j], pb);
    epbs[lm] = __expf(pb);
    float n4=0.f, n6=0.f;
    #pragma unroll
    for(int c=0;c<9;c++) n4 += f[c]*f[c];
    #pragma unroll
    for(int c=9;c<22;c++) n6 += f[c]*f[c];
    n4 = fmaxf(sqrtf(n4), 1e-12f);
    n6 = fmaxf(sqrtf(n6), 1e-12f);
    float s4 = __expf(log_s[0]), s6 = __expf(log_s[1]);
    float a4 = sqrtf(s4)/n4, a6 = sqrtf(s6)/n6;
    unsigned short* kph = Kgh + (size_t)idxp*32;
    unsigned short* kpl = Kgl + (size_t)idxp*32;
    #pragma unroll
    for(int c=0;c<22;c++){
      float qv = f[c] * (c<9 ? a4 : a6);
      unsigned short h = f2bf(qv);
      kph[c]=h; kpl[c]=f2bf(qv - bf2f(h));
    }
    #pragma unroll
    for(int c=22;c<32;c++){ kph[c]=0; kpl[c]=0; }
  }
  #pragma unroll
  for(int j4=0;j4<5;j4++){
    u32x4 wv;
    #pragma unroll
    for(int e=0;e<4;e++){
      int c = seg*20 + j4*4 + e;
      float pv;
      if(c<54){ int i=c/6, jj=c-6*i; pv = f[i]*y[jj]; }
      else if(c<132){ int cc=c-54; int i=cc/6, jj=cc-6*i; pv = f[9+i]*y[jj]; }
      else if(c==132) pv = 1.0f;
      else pv = 0.0f;
      wv[e] = pk2r(pv);
    }
    *(u32x4*)&Pbuf[lm*164 + seg*20 + j4*4] = wv;
  }
  __syncthreads();
  f32x4 acc[3];
  #pragma unroll
  for(int ft=0;ft<3;ft++)
    #pragma unroll
    for(int i=0;i<4;i++) acc[ft][i]=0.f;
  for(int kc=0;kc<5;kc++){
    const u32x4* ap = (const u32x4*)&Pbuf[lm*164 + kc*32 + quad*8];
    s16x8 Ah, Al;
    unpk(ap[0], ap[1], Ah, Al);
    #pragma unroll
    for(int ft=0;ft<3;ft++){
      int ftg = w2*3 + ft;
      size_t bo = (size_t)(ftg*16+lm)*160 + kc*32 + quad*8;
      s16x8 Bh = *(const s16x8*)(WBH + bo);
      s16x8 Bl = *(const s16x8*)(WBL + bo);
      f32x4 a = acc[ft];
      a = __builtin_amdgcn_mfma_f32_16x16x32_bf16(Al, Bl, a, 0,0,0);
      a = __builtin_amdgcn_mfma_f32_16x16x32_bf16(Al, Bh, a, 0,0,0);
      a = __builtin_amdgcn_mfma_f32_16x16x32_bf16(Ah, Bl, a, 0,0,0);
      a = __builtin_amdgcn_mfma_f32_16x16x32_bf16(Ah, Bh, a, 0,0,0);
      acc[ft] = a;
    }
  }
  #pragma unroll
  for(int r=0;r<4;r++){
    float e = epbs[quad*4 + r];
    #pragma unroll
    for(int ft=0;ft<3;ft++){
      int ftg = w2*3 + ft;
      Po[(ftg*16+lm)*17 + quad*4 + r] = (unsigned)f2h(acc[ft][r]*e);
    }
  }
  __syncthreads();
  unsigned int* vO32 = (unsigned int*)(Vg + (size_t)panel*96*64);
  #pragma unroll
  for(int wv=0; wv<6; wv++){
    int idx2 = wv*128 + tid;
    int g = idx2 >> 3, j = idx2 & 7;
    unsigned lo = Po[g*17 + 2*j] & 0xFFFFu;
    unsigned hi = Po[g*17 + 2*j + 1] & 0xFFFFu;
    vO32[g*32 + mt*8 + j] = lo | (hi<<16);
  }
}

// ---------------------------------------------------------------- k_attn
// grid 512 = 4b(fast) x 4kh x 32qb; block 512 (8 waves), BM=128, 16 panels,
// 2 blocks/CU. SOFTWARE-PIPELINED across the barrier: per iter, PV of the
// PREVIOUS iteration (from Es[prev] + V-register dbuf) runs between this
// iter's K/V load issue and the S phase — the independent PV work covers
// the load latency. Single lgkm-only barrier per iter; Es double-buffered
// (WAR separated by the intervening barrier). VGPR ~115 < 128 cap.
#define EST 72
__launch_bounds__(512, 4)
__global__ void k_attn(const unsigned short* __restrict__ Kgh,
                       const unsigned short* __restrict__ Kgl,
                       const unsigned short* __restrict__ Vg,
                       float* __restrict__ ctx0){
  __shared__ __align__(16) unsigned short Es[2][128*EST];   // 36864 B
  int tid = threadIdx.x;
  int lane = tid & 63, w = tid >> 6;
  int lm = lane & 15, quad = lane >> 4;
  int blk = blockIdx.x;
  int b = blk & 3, kh = (blk>>2)&3, qb = blk >> 4;   // qb 0..31
  int qrow0 = qb * 128;
  const unsigned short* KhB = Kgh + (size_t)b*NN*32;
  const unsigned short* KlB = Kgl + (size_t)b*NN*32;
  const unsigned short* VB  = Vg  + (size_t)b*64*96*64;
  float* ctx = ctx0 + (size_t)kh*CTXS + (size_t)b*NN*96;

  int sq = w & 3;    // q-tile pair {2sq,2sq+1}
  int sk = w >> 2;   // S k-tile pair {2sk,2sk+1}; PV f-group {3sk..3sk+2}

  s16x8 qh[2], ql[2];
  #pragma unroll
  for(int q2=0;q2<2;q2++){
    size_t ro = (size_t)(qrow0 + (2*sq+q2)*16 + lm)*32 + (size_t)quad*8;
    qh[q2] = *(const s16x8*)(KhB + ro);
    ql[q2] = *(const s16x8*)(KlB + ro);
  }
  f32x4 acc[2][3];
  #pragma unroll
  for(int q2=0;q2<2;q2++)
    #pragma unroll
    for(int ft=0;ft<3;ft++)
      #pragma unroll
      for(int i=0;i<4;i++) acc[q2][ft][i]=0.f;

  f16x8 vvP[2][3], vvN[2][3];

  // ---- prologue: iter 0 S-phase + its V loads
  {
    int key0 = (kh*16)*64;
    s16x8 kfh[2], kfl[2];
    #pragma unroll
    for(int k2=0;k2<2;k2++){
      size_t ko = (size_t)(key0 + (2*sk+k2)*16 + lm)*32 + (size_t)quad*8;
      kfh[k2] = *(const s16x8*)(KhB + ko);
      kfl[k2] = *(const s16x8*)(KlB + ko);
    }
    #pragma unroll
    for(int ks=0;ks<2;ks++)
      #pragma unroll
      for(int ft=0;ft<3;ft++){
        size_t vo = (size_t)(kh*16)*96*64 + (size_t)((3*sk+ft)*16+lm)*64 + ks*32 + quad*8;
        vvP[ks][ft] = *(const f16x8*)(VB + vo);
      }
    #pragma unroll
    for(int k2=0;k2<2;k2++)
      #pragma unroll
      for(int q2=0;q2<2;q2++){
        f32x4 s = {0.f,0.f,0.f,0.f};
        s = __builtin_amdgcn_mfma_f32_16x16x32_bf16(kfl[k2], qh[q2], s, 0,0,0);
        s = __builtin_amdgcn_mfma_f32_16x16x32_bf16(kfh[k2], ql[q2], s, 0,0,0);
        s = __builtin_amdgcn_mfma_f32_16x16x32_bf16(kfh[k2], qh[q2], s, 0,0,0);
        unsigned u01 = (unsigned)f2h(__expf(s[0])) | ((unsigned)f2h(__expf(s[1]))<<16);
        unsigned u23 = (unsigned)f2h(__expf(s[2])) | ((unsigned)f2h(__expf(s[3]))<<16);
        int row = (2*sq+q2)*16 + lm;
        int key = (2*sk+k2)*16 + quad*4;
        *(u32x2*)&Es[0][row*EST + key] = (u32x2){u01, u23};
      }
    barrier_lds();
  }

  // ---- main loop: iter it does loads[it], PV[it-1], S[it], barrier
  #pragma unroll 1
  for(int it=1; it<16; ++it){
    int cur = it&1, prv = cur^1;
    int panel = kh*16 + it;
    int key0 = panel*64;
    // issue K[it] loads
    s16x8 kfh[2], kfl[2];
    #pragma unroll
    for(int k2=0;k2<2;k2++){
      size_t ko = (size_t)(key0 + (2*sk+k2)*16 + lm)*32 + (size_t)quad*8;
      kfh[k2] = *(const s16x8*)(KhB + ko);
      kfl[k2] = *(const s16x8*)(KlB + ko);
    }
    // issue V[it] loads
    #pragma unroll
    for(int ks=0;ks<2;ks++)
      #pragma unroll
      for(int ft=0;ft<3;ft++){
        size_t vo = (size_t)panel*96*64 + (size_t)((3*sk+ft)*16+lm)*64 + ks*32 + quad*8;
        vvN[ks][ft] = *(const f16x8*)(VB + vo);
      }
    // PV of iter it-1 (Es[prv] + vvP regs) — covers the loads above
    #pragma unroll
    for(int ks=0;ks<2;ks++){
      #pragma unroll
      for(int q2=0;q2<2;q2++){
        f16x8 e = *(const f16x8*)&Es[prv][((2*sq+q2)*16 + lm)*EST + ks*32 + quad*8];
        #pragma unroll
        for(int ft=0;ft<3;ft++)
          acc[q2][ft] = __builtin_amdgcn_mfma_f32_16x16x32_f16(e, vvP[ks][ft], acc[q2][ft], 0,0,0);
      }
    }
    // S of iter it (K landed during PV)
    #pragma unroll
    for(int k2=0;k2<2;k2++)
      #pragma unroll
      for(int q2=0;q2<2;q2++){
        f32x4 s = {0.f,0.f,0.f,0.f};
        s = __builtin_amdgcn_mfma_f32_16x16x32_bf16(kfl[k2], qh[q2], s, 0,0,0);
        s = __builtin_amdgcn_mfma_f32_16x16x32_bf16(kfh[k2], ql[q2], s, 0,0,0);
        s = __builtin_amdgcn_mfma_f32_16x16x32_bf16(kfh[k2], qh[q2], s, 0,0,0);
        unsigned u01 = (unsigned)f2h(__expf(s[0])) | ((unsigned)f2h(__expf(s[1]))<<16);
        unsigned u23 = (unsigned)f2h(__expf(s[2])) | ((unsigned)f2h(__expf(s[3]))<<16);
        int row = (2*sq+q2)*16 + lm;
        int key = (2*sk+k2)*16 + quad*4;
        *(u32x2*)&Es[cur][row*EST + key] = (u32x2){u01, u23};
      }
    barrier_lds();   // Es[cur] visible; V[it] loads still in flight OK (vmcnt untouched)
    // rotate V buffers
    #pragma unroll
    for(int ks=0;ks<2;ks++)
      #pragma unroll
      for(int ft=0;ft<3;ft++)
        vvP[ks][ft] = vvN[ks][ft];
  }
  // ---- epilogue: PV of iter 15
  #pragma unroll
  for(int ks=0;ks<2;ks++){
    #pragma unroll
    for(int q2=0;q2<2;q2++){
      f16x8 e = *(const f16x8*)&Es[15&1][((2*sq+q2)*16 + lm)*EST + ks*32 + quad*8];
      #pragma unroll
      for(int ft=0;ft<3;ft++)
        acc[q2][ft] = __builtin_amdgcn_mfma_f32_16x16x32_f16(e, vvP[ks][ft], acc[q2][ft], 0,0,0);
    }
  }
  #pragma unroll
  for(int q2=0;q2<2;q2++){
    #pragma unroll
    for(int ft=0;ft<3;ft++){
      int col = (3*sk+ft)*16 + lm;
      #pragma unroll
      for(int r=0;r<4;r++){
        int row = qrow0 + (2*sq+q2)*16 + quad*4 + r;
        ctx[(size_t)row*96 + col] = acc[q2][ft][r];
      }
    }
  }
}

// ---------------------------------------------------------------- k_out
// grid 512 x 256: block = (64 points, typ): typ0 -> d4 paths, typ1 -> d6.
__launch_bounds__(256, 2)
__global__ void k_out(const float* __restrict__ feat, const float* __restrict__ ctxA,
                      const float* __restrict__ w3jout, float* __restrict__ out){
  __shared__ float gbuf[64*45];
  __shared__ float fbuf[64*24];
  __shared__ float dls[4*64*13];
  __shared__ float inv[64];
  int tid = threadIdx.x;
  int typ = blockIdx.x & 1;
  int n0 = (blockIdx.x>>1)*64;
  int gc0 = typ*44;
  for(int i=tid;i<64*44;i+=256){
    int pt=i/44, c=i-pt*44;
    const float* base = ctxA + (size_t)(n0+pt)*96 + gc0 + c;
    gbuf[pt*45+c] = base[0]+base[CTXS]+base[2*CTXS]+base[3*CTXS];
  }
  for(int i=tid;i<64*22;i+=256){
    int pt=i/22, c=i-pt*22;
    fbuf[pt*24+c] = feat[(size_t)(n0+pt)*22+c];
  }
  if(tid<64){
    const float* bd = ctxA + (size_t)(n0+tid)*96 + 88;
    inv[tid] = 1.0f/(bd[0]+bd[CTXS]+bd[2*CTXS]+bd[3*CTXS]);
  }
  __syncthreads();
  int lane = tid&63, w = tid>>6;
  float fR[13], gR[13], d[13];
  {
    int FB = (w&2)?9:0;
    int fn = (w&2)?13:9;
    #pragma unroll 13
    for(int i=0;i<13;i++) fR[i] = (i<fn) ? fbuf[lane*24 + FB + i] : 0.f;
    int GBl = (w==0)?0:(w==1)?9:(w==2)?22:31;
    int jn = (w&1)?13:9;
    #pragma unroll 13
    for(int j=0;j<13;j++) gR[j] = (j<jn) ? gbuf[lane*45 + GBl + j] : 0.f;
  }
  #pragma unroll 13
  for(int k=0;k<13;k++) d[k]=0.f;

#define PATHR(ID,JD,KD,WO) \
  _Pragma("unroll") \
  for(int i=0;i<(ID);i++){ float fv=fR[i]; \
    _Pragma("unroll") \
    for(int j=0;j<(JD);j++){ float val=fv*gR[j]; \
      const float* wp = w3jout + (WO) + (i*(JD)+j)*(KD); \
      _Pragma("unroll") \
      for(int k=0;k<(KD);k++) d[k] = fmaf(val, wp[k], d[k]); } }

  int pcase = typ*4 + w;
  switch(pcase){
    case 0: PATHR(9,9,9, 0)       break;
    case 1: PATHR(9,13,9, 729)    break;
    case 2: PATHR(13,9,9, 1782)   break;
    case 3: PATHR(13,13,9, 2835)  break;
    case 4: PATHR(9,9,13, 4356)   break;
    case 5: PATHR(9,13,13, 5409)  break;
    case 6: PATHR(13,9,13, 6930)  break;
    default:PATHR(13,13,13, 8451) break;
  }
#undef PATHR
  {
    float* dp = &dls[(w*64+lane)*13];
    #pragma unroll 13
    for(int k=0;k<13;k++) dp[k]=d[k];
  }
  __syncthreads();
  {
    int KD = typ?13:9;
    int kb = typ?9:0;
    int pt = tid&63, kc = tid>>6;
    float iv = inv[pt];
    #pragma unroll
    for(int e=0;e<4;e++){
      int k = kc*4+e;
      if(k<KD){
        float s = dls[(0*64+pt)*13+k] + dls[(1*64+pt)*13+k]
                + dls[(2*64+pt)*13+k] + dls[(3*64+pt)*13+k];
        out[(size_t)(n0+pt)*22 + kb + k] = s*iv;
      }
    }
  }
}

// ---------------------------------------------------------------- launch
extern "C" void kernel_launch(void* const* d_in, const int* in_sizes, int n_in,
                              void* d_out, int out_size, void* d_ws, size_t ws_size,
                              hipStream_t stream){
  (void)in_sizes; (void)n_in; (void)out_size; (void)ws_size;
  const float* feat =(const float*)d_in[0];
  const float* sh   =(const float*)d_in[1];
  const float* log_s=(const float*)d_in[2];
  const float* pos_w=(const float*)d_in[3];
  const float* pos_b=(const float*)d_in[4];
  const float* wli  =(const float*)d_in[5];
  const float* wval =(const float*)d_in[6];
  const float* wout =(const float*)d_in[7];
  const float* wlo  =(const float*)d_in[8];
  float* outp=(float*)d_out;
  float* wsf=(float*)d_ws;

  unsigned short* Kgh=(unsigned short*)((char*)d_ws + OFFB_KGH);
  unsigned short* Kgl=(unsigned short*)((char*)d_ws + OFFB_KGL);
  unsigned short* Vg =(unsigned short*)((char*)d_ws + OFFB_VG);
  unsigned short* WBH=(unsigned short*)((char*)d_ws + OFFB_WBH);
  unsigned short* WBL=(unsigned short*)((char*)d_ws + OFFB_WBL);

  hipLaunchKernelGGL(k_tab, dim3(14), dim3(256), 0, stream,
                     wsf+OFF_W3JVAL, wsf+OFF_W3JOUT);
  hipLaunchKernelGGL(k_weights, dim3(16), dim3(64), 0, stream,
                     wli, wval, wout, wlo, wsf+OFF_W3JVAL, WBH, WBL);
  hipLaunchKernelGGL(k_prep, dim3(1024), dim3(128), 0, stream,
                     feat, sh, log_s, pos_w, pos_b, WBH, WBL,
                     Kgh, Kgl, Vg);
  hipLaunchKernelGGL(k_attn, dim3(512), dim3(512), 0, stream,
                     Kgh, Kgl, Vg, wsf+OFF_CTX0);
  hipLaunchKernelGGL(k_out, dim3(512), dim3(256), 0, stream,
                     feat, wsf+OFF_CTX0, wsf+OFF_W3JOUT, outp);
}